// Round 7
// baseline (284.738 us; speedup 1.0000x reference)
//
#include <hip/hip_runtime.h>
#include <hip/hip_bf16.h>
#include <math.h>

#define L 2048
#define D 256
#define NEG_FLT_MAX (-3.402823466e38f)

typedef __attribute__((ext_vector_type(8))) short bf16x8;
typedef __attribute__((ext_vector_type(4))) float f32x4;
typedef __attribute__((ext_vector_type(4))) int i32x4;

__device__ __forceinline__ unsigned short f2bf(float f) {
    union { float f; unsigned int u; } v; v.f = f;
    unsigned int r = v.u + 0x7FFFu + ((v.u >> 16) & 1u);   // RNE
    return (unsigned short)(r >> 16);
}

// --- prep: fused {Wv transpose -> LDS} + {value @ Wv + bv -> Vt bf16}
//     + side-job {Wo transpose -> Wot global}
// 32x64 tile, grid (256,4) = 1024 blocks -> 4 blocks/CU
__global__ __launch_bounds__(256, 4) void prep_kernel(
    const float* __restrict__ value, const float* __restrict__ Wv,
    const float* __restrict__ bv, const float* __restrict__ Wo,
    unsigned short* __restrict__ Vt, unsigned short* __restrict__ Wot) {
    const int tid = threadIdx.x;
    const int wave = tid >> 6, lane = tid & 63;
    const int lm = lane & 15, q = lane >> 4;
    const int rh = wave >> 1;          // row half (16 rows each)
    const int nh = wave & 1;           // n half (32 cols each)
    const int m0 = blockIdx.x * 32;
    const int n0 = blockIdx.y * 64;

    __shared__ __align__(16) unsigned short Wlds[64][264];   // [n-local][k] bf16

    // side job: Wo transpose (64 elements per block, 1024 blocks cover 64K)
    {
        int bid = blockIdx.y * 256 + blockIdx.x;
        if (tid < 64) {
            int e = bid * 64 + tid;
            int k = e >> 8, n = e & 255;
            Wot[n * 256 + k] = f2bf(Wo[k * 256 + n]);
        }
    }

    // stage Wv[0:256][n0:n0+64] -> Wlds[n][k], coalesced f32 reads
    {
        int krow = tid >> 4;           // 0..15
        int nrel = (tid & 15) * 4;     // 0..60
#pragma unroll
        for (int p = 0; p < 16; p++) {
            int k = p * 16 + krow;
            f32x4 w = *reinterpret_cast<const f32x4*>(Wv + (size_t)k * 256 + n0 + nrel);
            Wlds[nrel + 0][k] = f2bf(w[0]);
            Wlds[nrel + 1][k] = f2bf(w[1]);
            Wlds[nrel + 2][k] = f2bf(w[2]);
            Wlds[nrel + 3][k] = f2bf(w[3]);
        }
    }
    __syncthreads();

    const int nl0 = nh * 32 + lm;          // local n, fragment 0
    const int nl1 = nh * 32 + 16 + lm;     // local n, fragment 1
    const int arow = m0 + rh * 16 + lm;

    f32x4 acc[2];
    acc[0] = (f32x4)(0.f); acc[1] = (f32x4)(0.f);

    const float* ap = value + (size_t)arow * 256;
    f32x4 pa0 = *reinterpret_cast<const f32x4*>(ap + q * 8);
    f32x4 pa1 = *reinterpret_cast<const f32x4*>(ap + q * 8 + 4);

    for (int k0 = 0; k0 < 256; k0 += 32) {
        f32x4 a0 = pa0, a1 = pa1;
        if (k0 < 224) {
            int kq = k0 + 32 + q * 8;
            pa0 = *reinterpret_cast<const f32x4*>(ap + kq);
            pa1 = *reinterpret_cast<const f32x4*>(ap + kq + 4);
        }
        bf16x8 b0 = *reinterpret_cast<const bf16x8*>(&Wlds[nl0][k0 + q * 8]);
        bf16x8 b1 = *reinterpret_cast<const bf16x8*>(&Wlds[nl1][k0 + q * 8]);
        bf16x8 afr;
#pragma unroll
        for (int e = 0; e < 4; e++) afr[e] = (short)f2bf(a0[e]);
#pragma unroll
        for (int e = 0; e < 4; e++) afr[4 + e] = (short)f2bf(a1[e]);
        acc[0] = __builtin_amdgcn_mfma_f32_16x16x32_bf16(afr, b0, acc[0], 0, 0, 0);
        acc[1] = __builtin_amdgcn_mfma_f32_16x16x32_bf16(afr, b1, acc[1], 0, 0, 0);
    }

    int mrow = m0 + rh * 16 + q * 4;       // rows mrow..mrow+3
    int b = mrow >> 11;
    int j = mrow & 2047;
#pragma unroll
    for (int nf = 0; nf < 2; nf++) {
        int n = n0 + nh * 32 + nf * 16 + lm;
        float bias_n = bv[n];
        const f32x4& a = acc[nf];
        unsigned short* dst = Vt + (size_t)b * (D * L) + (size_t)n * L + j;
        ushort4 pk;
        pk.x = f2bf(a[0] + bias_n);
        pk.y = f2bf(a[1] + bias_n);
        pk.z = f2bf(a[2] + bias_n);
        pk.w = f2bf(a[3] + bias_n);
        *reinterpret_cast<ushort4*>(dst) = pk;
    }
}

// --- fused mask + no-max softmax + P@V + /l + @Wo + bo, ONE-WAVE blocks -
// 512 blocks x 64 threads. Each wave owns 16 rows x all 2048 j x all 256 n.
// Lane (q,lm) IS the MFMA A-fragment slot: row lm, j = q*8..q*8+7 -> the
// lane's own masked-exp output feeds its own MFMA. No Plds, no barriers,
// no redistribution, no redundancy. j-tile = 32 (= MFMA K).
// __launch_bounds__(64,1): VGPR budget ~512 -> the double-buffer
// (acc 64 + 2x16 Vt frags 128 + 2x logits 48) actually fits, so 22 loads
// stay in flight across a full tile of compute (ILP latency hiding).
// Logit coalescing: per tile each row's slice = 32j x 4B = one full 128B
// line; 16 lines/instr, all fully consumed.
__global__ __launch_bounds__(64, 1) void attn_kernel(
    const float* __restrict__ atten, const float* __restrict__ mask,
    const int* __restrict__ pad, const unsigned short* __restrict__ Vt,
    const unsigned short* __restrict__ Wot, const float* __restrict__ bo,
    float* __restrict__ out) {
    const int g = blockIdx.x;          // 0..511
    const int b = g >> 7;
    const int i0 = (g & 127) * 16;
    const int lane = threadIdx.x & 63;
    const int lm = lane & 15, q = lane >> 4;

    __shared__ __align__(16) unsigned short A_lds[16][264];
    __shared__ float l_lds[16];

    f32x4 acc[16];
#pragma unroll
    for (int nf = 0; nf < 16; nf++) acc[nf] = (f32x4)(0.f);
    float lsum = 0.f;

    // per-lane logit source: row i0+lm, j base q*8
    const size_t rowoff = ((size_t)(b * L + i0 + lm)) * L + q * 8;
    const float* at_p = atten + rowoff;
    const float* mk_p = mask + rowoff;
    const int*   pd_p = pad + rowoff;
    const unsigned short* vt_b = Vt + (size_t)b * (D * L) + q * 8;

    // double-buffered register state (A/B named -> static indexing)
    f32x4 aA0, aA1, mA0, mA1, aB0, aB1, mB0, mB1;
    i32x4 pA0, pA1, pB0, pB1;
    bf16x8 vA[16], vB[16];

    // prologue: tile 0 -> A
    aA0 = *reinterpret_cast<const f32x4*>(at_p);
    aA1 = *reinterpret_cast<const f32x4*>(at_p + 4);
    mA0 = *reinterpret_cast<const f32x4*>(mk_p);
    mA1 = *reinterpret_cast<const f32x4*>(mk_p + 4);
    pA0 = *reinterpret_cast<const i32x4*>(pd_p);
    pA1 = *reinterpret_cast<const i32x4*>(pd_p + 4);
#pragma unroll
    for (int nf = 0; nf < 16; nf++)
        vA[nf] = *reinterpret_cast<const bf16x8*>(vt_b + (size_t)(nf * 16 + lm) * L);

    for (int jt = 0; jt < 64; jt += 2) {
        // ---- even tile jt: prefetch jt+1 -> B, consume A ----------------
        {
            const int jn = (jt + 1) * 32;
            aB0 = *reinterpret_cast<const f32x4*>(at_p + jn);
            aB1 = *reinterpret_cast<const f32x4*>(at_p + jn + 4);
            mB0 = *reinterpret_cast<const f32x4*>(mk_p + jn);
            mB1 = *reinterpret_cast<const f32x4*>(mk_p + jn + 4);
            pB0 = *reinterpret_cast<const i32x4*>(pd_p + jn);
            pB1 = *reinterpret_cast<const i32x4*>(pd_p + jn + 4);
#pragma unroll
            for (int nf = 0; nf < 16; nf++)
                vB[nf] = *reinterpret_cast<const bf16x8*>(
                    vt_b + (size_t)(nf * 16 + lm) * L + jn);

            bf16x8 afr;
#pragma unroll
            for (int e = 0; e < 4; e++) {
                float sv = (mA0[e] < 0.5f) ? NEG_FLT_MAX : aA0[e];
                sv = (pA0[e] == 0) ? -INFINITY : sv;
                float pv = __expf(sv);
                lsum += pv;
                afr[e] = (short)f2bf(pv);
                float sw = (mA1[e] < 0.5f) ? NEG_FLT_MAX : aA1[e];
                sw = (pA1[e] == 0) ? -INFINITY : sw;
                float pw = __expf(sw);
                lsum += pw;
                afr[4 + e] = (short)f2bf(pw);
            }
#pragma unroll
            for (int nf = 0; nf < 16; nf++)
                acc[nf] = __builtin_amdgcn_mfma_f32_16x16x32_bf16(
                    afr, vA[nf], acc[nf], 0, 0, 0);
        }
        // ---- odd tile jt+1: prefetch jt+2 -> A, consume B ---------------
        {
            if (jt < 62) {
                const int jn = (jt + 2) * 32;
                aA0 = *reinterpret_cast<const f32x4*>(at_p + jn);
                aA1 = *reinterpret_cast<const f32x4*>(at_p + jn + 4);
                mA0 = *reinterpret_cast<const f32x4*>(mk_p + jn);
                mA1 = *reinterpret_cast<const f32x4*>(mk_p + jn + 4);
                pA0 = *reinterpret_cast<const i32x4*>(pd_p + jn);
                pA1 = *reinterpret_cast<const i32x4*>(pd_p + jn + 4);
#pragma unroll
                for (int nf = 0; nf < 16; nf++)
                    vA[nf] = *reinterpret_cast<const bf16x8*>(
                        vt_b + (size_t)(nf * 16 + lm) * L + jn);
            }
            bf16x8 afr;
#pragma unroll
            for (int e = 0; e < 4; e++) {
                float sv = (mB0[e] < 0.5f) ? NEG_FLT_MAX : aB0[e];
                sv = (pB0[e] == 0) ? -INFINITY : sv;
                float pv = __expf(sv);
                lsum += pv;
                afr[e] = (short)f2bf(pv);
                float sw = (mB1[e] < 0.5f) ? NEG_FLT_MAX : aB1[e];
                sw = (pB1[e] == 0) ? -INFINITY : sw;
                float pw = __expf(sw);
                lsum += pw;
                afr[4 + e] = (short)f2bf(pw);
            }
#pragma unroll
            for (int nf = 0; nf < 16; nf++)
                acc[nf] = __builtin_amdgcn_mfma_f32_16x16x32_bf16(
                    afr, vB[nf], acc[nf], 0, 0, 0);
        }
    }

    // l-reduction: lanes lm, lm+16, lm+32, lm+48 share row lm
    lsum += __shfl_xor(lsum, 16);
    lsum += __shfl_xor(lsum, 32);
    if (lane < 16) l_lds[lm] = lsum;
    __syncthreads();

    // normalize + in-wave transpose (C-layout -> A-frag layout) via LDS
    float linv[4];
#pragma unroll
    for (int rg = 0; rg < 4; rg++) linv[rg] = 1.f / l_lds[q * 4 + rg];
#pragma unroll
    for (int nf = 0; nf < 16; nf++) {
        int n = nf * 16 + lm;
#pragma unroll
        for (int rg = 0; rg < 4; rg++)
            A_lds[q * 4 + rg][n] = f2bf(acc[nf][rg] * linv[rg]);
    }
    __syncthreads();

    // out-projection: [16][256] @ Wo + bo (Wot L2-hot, shared by all blocks)
    f32x4 oacc[16];
#pragma unroll
    for (int nf = 0; nf < 16; nf++) oacc[nf] = (f32x4)(0.f);
    for (int k0 = 0; k0 < 256; k0 += 32) {
        bf16x8 afr = *reinterpret_cast<const bf16x8*>(&A_lds[lm][k0 + q * 8]);
#pragma unroll
        for (int nf = 0; nf < 16; nf++) {
            bf16x8 w = *reinterpret_cast<const bf16x8*>(
                Wot + (size_t)(nf * 16 + lm) * 256 + k0 + q * 8);
            oacc[nf] = __builtin_amdgcn_mfma_f32_16x16x32_bf16(
                afr, w, oacc[nf], 0, 0, 0);
        }
    }
#pragma unroll
    for (int nf = 0; nf < 16; nf++) {
        int n = nf * 16 + lm;
        float bias_n = bo[n];
#pragma unroll
        for (int rg = 0; rg < 4; rg++)
            out[((size_t)(b * L + i0 + q * 4 + rg)) * 256 + n] = oacc[nf][rg] + bias_n;
    }
}

extern "C" void kernel_launch(void* const* d_in, const int* in_sizes, int n_in,
                              void* d_out, int out_size, void* d_ws, size_t ws_size,
                              hipStream_t stream) {
    (void)in_sizes; (void)n_in; (void)out_size; (void)ws_size;
    const float* atten = (const float*)d_in[0];
    const float* value = (const float*)d_in[1];
    const float* mask  = (const float*)d_in[2];
    const int*   pad   = (const int*)d_in[3];
    const float* Wv    = (const float*)d_in[4];
    const float* bv    = (const float*)d_in[5];
    const float* Wo    = (const float*)d_in[6];
    const float* bo    = (const float*)d_in[7];
    float* out = (float*)d_out;

    char* ws = (char*)d_ws;
    unsigned short* Vt  = (unsigned short*)(ws);              // 4 MB  bf16 [B][D][L]
    unsigned short* Wot = (unsigned short*)(ws + 4194304);    // 128 KB

    prep_kernel<<<dim3(256, 4), 256, 0, stream>>>(value, Wv, bv, Wo, Vt, Wot);
    attn_kernel<<<512, 64, 0, stream>>>(atten, mask, pad, Vt, Wot, bo, out);
}

// Round 8
// 274.717 us; speedup vs baseline: 1.0365x; 1.0365x over previous
//
#include <hip/hip_runtime.h>
#include <hip/hip_bf16.h>
#include <math.h>

#define L 2048
#define D 256
#define NEG_FLT_MAX (-3.402823466e38f)

typedef __attribute__((ext_vector_type(8))) short bf16x8;
typedef __attribute__((ext_vector_type(4))) float f32x4;
typedef __attribute__((ext_vector_type(4))) int i32x4;

__device__ __forceinline__ unsigned short f2bf(float f) {
    union { float f; unsigned int u; } v; v.f = f;
    unsigned int r = v.u + 0x7FFFu + ((v.u >> 16) & 1u);   // RNE
    return (unsigned short)(r >> 16);
}

// --- prep: fused {Wv transpose -> LDS} + {value @ Wv + bv -> Vt bf16}
//     + side-job {Wo transpose -> Wot global}
__global__ __launch_bounds__(256, 4) void prep_kernel(
    const float* __restrict__ value, const float* __restrict__ Wv,
    const float* __restrict__ bv, const float* __restrict__ Wo,
    unsigned short* __restrict__ Vt, unsigned short* __restrict__ Wot) {
    const int tid = threadIdx.x;
    const int wave = tid >> 6, lane = tid & 63;
    const int lm = lane & 15, q = lane >> 4;
    const int rh = wave >> 1;
    const int nh = wave & 1;
    const int m0 = blockIdx.x * 32;
    const int n0 = blockIdx.y * 64;

    __shared__ __align__(16) unsigned short Wlds[64][264];

    {
        int bid = blockIdx.y * 256 + blockIdx.x;
        if (tid < 64) {
            int e = bid * 64 + tid;
            int k = e >> 8, n = e & 255;
            Wot[n * 256 + k] = f2bf(Wo[k * 256 + n]);
        }
    }
    {
        int krow = tid >> 4;
        int nrel = (tid & 15) * 4;
#pragma unroll
        for (int p = 0; p < 16; p++) {
            int k = p * 16 + krow;
            f32x4 w = *reinterpret_cast<const f32x4*>(Wv + (size_t)k * 256 + n0 + nrel);
            Wlds[nrel + 0][k] = f2bf(w[0]);
            Wlds[nrel + 1][k] = f2bf(w[1]);
            Wlds[nrel + 2][k] = f2bf(w[2]);
            Wlds[nrel + 3][k] = f2bf(w[3]);
        }
    }
    __syncthreads();

    const int nl0 = nh * 32 + lm;
    const int nl1 = nh * 32 + 16 + lm;
    const int arow = m0 + rh * 16 + lm;

    f32x4 acc[2];
    acc[0] = (f32x4)(0.f); acc[1] = (f32x4)(0.f);

    const float* ap = value + (size_t)arow * 256;
    f32x4 pa0 = *reinterpret_cast<const f32x4*>(ap + q * 8);
    f32x4 pa1 = *reinterpret_cast<const f32x4*>(ap + q * 8 + 4);

    for (int k0 = 0; k0 < 256; k0 += 32) {
        f32x4 a0 = pa0, a1 = pa1;
        if (k0 < 224) {
            int kq = k0 + 32 + q * 8;
            pa0 = *reinterpret_cast<const f32x4*>(ap + kq);
            pa1 = *reinterpret_cast<const f32x4*>(ap + kq + 4);
        }
        bf16x8 b0 = *reinterpret_cast<const bf16x8*>(&Wlds[nl0][k0 + q * 8]);
        bf16x8 b1 = *reinterpret_cast<const bf16x8*>(&Wlds[nl1][k0 + q * 8]);
        bf16x8 afr;
#pragma unroll
        for (int e = 0; e < 4; e++) afr[e] = (short)f2bf(a0[e]);
#pragma unroll
        for (int e = 0; e < 4; e++) afr[4 + e] = (short)f2bf(a1[e]);
        acc[0] = __builtin_amdgcn_mfma_f32_16x16x32_bf16(afr, b0, acc[0], 0, 0, 0);
        acc[1] = __builtin_amdgcn_mfma_f32_16x16x32_bf16(afr, b1, acc[1], 0, 0, 0);
    }

    int mrow = m0 + rh * 16 + q * 4;
    int b = mrow >> 11;
    int j = mrow & 2047;
#pragma unroll
    for (int nf = 0; nf < 2; nf++) {
        int n = n0 + nh * 32 + nf * 16 + lm;
        float bias_n = bv[n];
        const f32x4& a = acc[nf];
        unsigned short* dst = Vt + (size_t)b * (D * L) + (size_t)n * L + j;
        ushort4 pk;
        pk.x = f2bf(a[0] + bias_n);
        pk.y = f2bf(a[1] + bias_n);
        pk.z = f2bf(a[2] + bias_n);
        pk.w = f2bf(a[3] + bias_n);
        *reinterpret_cast<ushort4*>(dst) = pk;
    }
}

// --- attn: mask + no-max softmax + P@V partials, HIGH-OCCUPANCY ---------
// 1024 blocks x 256 thr, launch_bounds(256,4) -> 4 blocks/CU = 16 waves/CU.
// TLP is the latency hider (round-1 evidence: 16 waves/CU -> 1.9 TB/s).
// Block = 16 rows x 1024 j (js half) x 256 n (4-wave n-split).
// j-tile 64: 3 logit loads (coalesced, lane = consecutive j) + 8 Vt frags
// per iter. P via Plds, 1 barrier/iter, double-buffered. No-max softmax
// => js partials combine by ADDITION in the output GEMM (no m/exp logic).
// Partial: 16x256 f32 acc + 16 l per block = 16.1 KB -> 17 MB total.
__global__ __launch_bounds__(256, 4) void attn_kernel(
    const float* __restrict__ atten, const float* __restrict__ mask,
    const int* __restrict__ pad, const unsigned short* __restrict__ Vt,
    float* __restrict__ part) {
    const int bid = blockIdx.x;                  // 0..1023
    const int g = (bid & 7) * 128 + (bid >> 3);  // XCD-chunked
    const int b = g >> 8;
    const int js = (g >> 7) & 1;
    const int i0 = (g & 127) * 16;
    const int tid = threadIdx.x;
    const int wave = tid >> 6, lane = tid & 63;
    const int lm = lane & 15, q = lane >> 4;
    const int r = tid >> 4;            // softmax row 0..15
    const int c4 = (tid & 15) * 4;     // j offset within 64-tile

    __shared__ __align__(16) unsigned short Plds[2][16][72];

    f32x4 acc[4];
#pragma unroll
    for (int nf = 0; nf < 4; nf++) acc[nf] = (f32x4)(0.f);
    float lsum = 0.f;

    const size_t rowoff = ((size_t)(b * L + i0 + r)) * L + js * 1024 + c4;
    const float* at_p = atten + rowoff;
    const float* mk_p = mask + rowoff;
    const int*   pd_p = pad + rowoff;
    const unsigned short* vt_b = Vt + (size_t)b * (D * L) + js * 1024;

    // depth-1 prefetch of logits (3 loads)
    f32x4 pa = *reinterpret_cast<const f32x4*>(at_p);
    f32x4 pm = *reinterpret_cast<const f32x4*>(mk_p);
    i32x4 pp = *reinterpret_cast<const i32x4*>(pd_p);

    for (int jt = 0; jt < 16; jt++) {
        const int j0 = jt * 64;
        // Vt fragments for this wave's 64-n range (issued first)
        bf16x8 bfr[2][4];
#pragma unroll
        for (int kk = 0; kk < 2; kk++)
#pragma unroll
            for (int nf = 0; nf < 4; nf++) {
                int n = wave * 64 + nf * 16 + lm;
                bfr[kk][nf] = *reinterpret_cast<const bf16x8*>(
                    vt_b + (size_t)n * L + j0 + kk * 32 + q * 8);
            }
        f32x4 a = pa, k = pm;
        i32x4 p = pp;
        if (jt < 15) {
            pa = *reinterpret_cast<const f32x4*>(at_p + j0 + 64);
            pm = *reinterpret_cast<const f32x4*>(mk_p + j0 + 64);
            pp = *reinterpret_cast<const i32x4*>(pd_p + j0 + 64);
        }
        // masked exp (no max subtraction; masked -> exp underflows to 0)
        ushort4 pk;
        float p0, p1, p2, p3;
        {
            float s0 = (k[0] < 0.5f) ? NEG_FLT_MAX : a[0];
            s0 = (p[0] == 0) ? -INFINITY : s0; p0 = __expf(s0);
            float s1 = (k[1] < 0.5f) ? NEG_FLT_MAX : a[1];
            s1 = (p[1] == 0) ? -INFINITY : s1; p1 = __expf(s1);
            float s2 = (k[2] < 0.5f) ? NEG_FLT_MAX : a[2];
            s2 = (p[2] == 0) ? -INFINITY : s2; p2 = __expf(s2);
            float s3 = (k[3] < 0.5f) ? NEG_FLT_MAX : a[3];
            s3 = (p[3] == 0) ? -INFINITY : s3; p3 = __expf(s3);
        }
        lsum += (p0 + p1) + (p2 + p3);
        pk.x = f2bf(p0); pk.y = f2bf(p1); pk.z = f2bf(p2); pk.w = f2bf(p3);

        const int par = jt & 1;
        *reinterpret_cast<ushort4*>(&Plds[par][r][c4]) = pk;
        __syncthreads();

        // P @ V
#pragma unroll
        for (int kk = 0; kk < 2; kk++) {
            bf16x8 afr = *reinterpret_cast<const bf16x8*>(
                &Plds[par][lm][kk * 32 + q * 8]);
#pragma unroll
            for (int nf = 0; nf < 4; nf++)
                acc[nf] = __builtin_amdgcn_mfma_f32_16x16x32_bf16(
                    afr, bfr[kk][nf], acc[nf], 0, 0, 0);
        }
    }

    // deferred l-reduction: 16 consecutive tids share row r
    lsum += __shfl_xor(lsum, 1);
    lsum += __shfl_xor(lsum, 2);
    lsum += __shfl_xor(lsum, 4);
    lsum += __shfl_xor(lsum, 8);

    // store partial: acc[16][256] f32 + l[16]
    float* pbase = part + (size_t)g * 4112;
#pragma unroll
    for (int nf = 0; nf < 4; nf++) {
        int n = wave * 64 + nf * 16 + lm;
#pragma unroll
        for (int rg = 0; rg < 4; rg++)
            pbase[(q * 4 + rg) * 256 + n] = acc[nf][rg];
    }
    if ((tid & 15) == 0) pbase[4096 + r] = lsum;
}

// --- output GEMM with fused js-pair combine (plain addition) ------------
// A row = (part_js0 + part_js1) / (l0 + l1), then @ Wo + bo -> out.
// 64x64 tile, grid (128,4) = 512 blocks.
__global__ __launch_bounds__(256, 2) void gemm_out_kernel(
    const float* __restrict__ part,
    const unsigned short* __restrict__ Wt,
    const float* __restrict__ bias,
    float* __restrict__ Cout) {
    const int wave = threadIdx.x >> 6;
    const int lane = threadIdx.x & 63;
    const int lm = lane & 15, q = lane >> 4;
    const int m0 = blockIdx.x * 64;
    const int n0 = blockIdx.y * 64;
    const int arow = m0 + wave * 16 + lm;
    const int b = arow >> 11;
    const int rg16 = (arow & 2047) >> 4;
    const int r_in = arow & 15;
    const float* pb0 = part + (size_t)(b * 256 + rg16) * 4112;
    const float* pb1 = pb0 + (size_t)128 * 4112;

    float linv = 1.f / (pb0[4096 + r_in] + pb1[4096 + r_in]);

    int ncol[4];
#pragma unroll
    for (int nf = 0; nf < 4; nf++) ncol[nf] = n0 + nf * 16 + lm;

    f32x4 acc[4];
#pragma unroll
    for (int nf = 0; nf < 4; nf++) acc[nf] = (f32x4)(0.f);

    for (int k0 = 0; k0 < 256; k0 += 32) {
        int kq = k0 + q * 8;
        bf16x8 bfr[4];
#pragma unroll
        for (int nf = 0; nf < 4; nf++)
            bfr[nf] = *reinterpret_cast<const bf16x8*>(Wt + (size_t)ncol[nf] * 256 + kq);
        f32x4 s0 = *reinterpret_cast<const f32x4*>(pb0 + r_in * 256 + kq)
                 + *reinterpret_cast<const f32x4*>(pb1 + r_in * 256 + kq);
        f32x4 s1 = *reinterpret_cast<const f32x4*>(pb0 + r_in * 256 + kq + 4)
                 + *reinterpret_cast<const f32x4*>(pb1 + r_in * 256 + kq + 4);
        bf16x8 afr;
#pragma unroll
        for (int e = 0; e < 4; e++) afr[e] = (short)f2bf(s0[e] * linv);
#pragma unroll
        for (int e = 0; e < 4; e++) afr[4 + e] = (short)f2bf(s1[e] * linv);
#pragma unroll
        for (int nf = 0; nf < 4; nf++)
            acc[nf] = __builtin_amdgcn_mfma_f32_16x16x32_bf16(
                afr, bfr[nf], acc[nf], 0, 0, 0);
    }

    int mrow = m0 + wave * 16 + q * 4;
#pragma unroll
    for (int nf = 0; nf < 4; nf++) {
        int n = ncol[nf];
        float bias_n = bias[n];
#pragma unroll
        for (int rg = 0; rg < 4; rg++)
            Cout[(size_t)(mrow + rg) * 256 + n] = acc[nf][rg] + bias_n;
    }
}

extern "C" void kernel_launch(void* const* d_in, const int* in_sizes, int n_in,
                              void* d_out, int out_size, void* d_ws, size_t ws_size,
                              hipStream_t stream) {
    (void)in_sizes; (void)n_in; (void)out_size; (void)ws_size;
    const float* atten = (const float*)d_in[0];
    const float* value = (const float*)d_in[1];
    const float* mask  = (const float*)d_in[2];
    const int*   pad   = (const int*)d_in[3];
    const float* Wv    = (const float*)d_in[4];
    const float* bv    = (const float*)d_in[5];
    const float* Wo    = (const float*)d_in[6];
    const float* bo    = (const float*)d_in[7];
    float* out = (float*)d_out;

    char* ws = (char*)d_ws;
    unsigned short* Vt  = (unsigned short*)(ws);              // 4 MB  bf16 [B][D][L]
    unsigned short* Wot = (unsigned short*)(ws + 4194304);    // 128 KB
    float* part = (float*)(ws + 4325376);                     // 1024 * 16448 B = 16.8 MB

    prep_kernel<<<dim3(256, 4), 256, 0, stream>>>(value, Wv, bv, Wo, Vt, Wot);
    attn_kernel<<<1024, 256, 0, stream>>>(atten, mask, pad, Vt, part);
    gemm_out_kernel<<<dim3(128, 4), 256, 0, stream>>>(part, Wot, bo, out);
}